// Round 3
// baseline (120.479 us; speedup 1.0000x reference)
//
#include <hip/hip_runtime.h>

// GraphAutoEncoder: one thread per graph (B=131072, N=8).
// Round-3 version: packed-fp32 (v_pk_*_f32) everywhere, min-based Gabriel
// blocking test, adjacency kept as float 0/1 (no bitmask<->float conversion).
// Latent arithmetic is bit-identical to the round-2 kernel (per-component pk
// rounding == scalar rounding), so the discrete Gabriel comparisons are
// unchanged.

typedef float v2 __attribute__((ext_vector_type(2)));

static __device__ __forceinline__ v2 sp(float s) { return (v2){s, s}; }
static __device__ __forceinline__ v2 fma2(v2 a, v2 b, v2 c) {
    return __builtin_elementwise_fma(a, b, c);
}
static __device__ __forceinline__ v2 ldv2(const float* p) {
    return *reinterpret_cast<const v2*>(p);
}

__global__ __launch_bounds__(256, 2) void gae_kernel(
    const float* __restrict__ x,        // (B,8)
    const float* __restrict__ enc_w1,   // (3,64)
    const float* __restrict__ enc_b1,   // (64,)
    const float* __restrict__ enc_w2,   // (64,2)
    const float* __restrict__ enc_b2,   // (2,)
    const float* __restrict__ gcn1_w,   // (2,32)
    const float* __restrict__ gcn1_b,   // (32,)
    const float* __restrict__ gcn2_w,   // (32,32)
    const float* __restrict__ gcn2_b,   // (32,)
    const float* __restrict__ dec_w1,   // (32,64)
    const float* __restrict__ dec_b1,   // (64,)
    const float* __restrict__ dec_w2,   // (64,3)
    const float* __restrict__ dec_b2,   // (3,)
    float* __restrict__ out_rec,        // (B,8)
    float* __restrict__ out_lat,        // (B,8,2)
    int B)
{
    const int b = blockIdx.x * blockDim.x + threadIdx.x;
    if (b >= B) return;

    // ---- load x[b, 0..7]: two float4 (32B/lane, coalesced) ----
    float xv[8];
    {
        const float4* xp = reinterpret_cast<const float4*>(x + (size_t)b * 8);
        float4 a = xp[0], c = xp[1];
        xv[0] = a.x; xv[1] = a.y; xv[2] = a.z; xv[3] = a.w;
        xv[4] = c.x; xv[5] = c.y; xv[6] = c.z; xv[7] = c.w;
    }
    v2 xv2[4];
    #pragma unroll
    for (int ip = 0; ip < 4; ++ip) xv2[ip] = (v2){xv[2 * ip], xv[2 * ip + 1]};

    // ---- encoder: p[i] = relu(xp_i @ W1 + b1) @ W2 + b2, xp_i = (0,x_i,i) ----
    // Per-component ops identical to scalar version -> latent bit-identical.
    v2 p[8];
    {
        const v2 b2v = ldv2(enc_b2);
        #pragma unroll
        for (int i = 0; i < 8; ++i) p[i] = b2v;
    }
    #pragma unroll 4
    for (int h = 0; h < 64; ++h) {
        const float wx = enc_w1[64 + h];    // W1[1][h]
        const float wi = enc_w1[128 + h];   // W1[2][h]
        const float bb = enc_b1[h];
        const v2 uxy = ldv2(enc_w2 + 2 * h); // (W2[h][0], W2[h][1])
        #pragma unroll
        for (int ip = 0; ip < 4; ++ip) {
            // c = i*wi + bb (uniform), t = x*wx + c, relu
            v2 c2 = fma2((v2){(float)(2 * ip), (float)(2 * ip + 1)}, sp(wi), sp(bb));
            v2 t2 = fma2(xv2[ip], sp(wx), c2);
            float t0 = fmaxf(t2.x, 0.0f);
            float t1 = fmaxf(t2.y, 0.0f);
            p[2 * ip]     = fma2(sp(t0), uxy, p[2 * ip]);
            p[2 * ip + 1] = fma2(sp(t1), uxy, p[2 * ip + 1]);
        }
    }

    // ---- write latent (B,8,2) ----
    {
        float4* lo = reinterpret_cast<float4*>(out_lat + (size_t)b * 16);
        lo[0] = make_float4(p[0].x, p[0].y, p[1].x, p[1].y);
        lo[1] = make_float4(p[2].x, p[2].y, p[3].x, p[3].y);
        lo[2] = make_float4(p[4].x, p[4].y, p[5].x, p[5].y);
        lo[3] = make_float4(p[6].x, p[6].y, p[7].x, p[7].y);
    }

    // ---- Gabriel graph -> a_hat as float 0/1 (diag = 1 self loop) ----
    float af[8][8];
    #pragma unroll
    for (int i = 0; i < 8; ++i)
        #pragma unroll
        for (int j = 0; j < 8; ++j) af[i][j] = (i == j) ? 1.0f : 0.0f;
    {
        // Discrete decisions: no fma contraction; ops mirror the reference's
        // elementwise arithmetic. r2 per DIRECTION (ulp-asymmetric, as ref).
        // any_k(d2 < r2)  <=>  (min_k d2) < r2   (fmin exact, data finite).
        #pragma clang fp contract(off)
        #pragma unroll
        for (int i = 0; i < 8; ++i) {
            #pragma unroll
            for (int j = i + 1; j < 8; ++j) {
                v2 mid = (p[i] + p[j]) * sp(0.5f);
                v2 di = p[i] - mid;  v2 si = di * di;  float r2i = si.x + si.y;
                v2 dj = p[j] - mid;  v2 sj = dj * dj;  float r2j = sj.x + sj.y;
                float dmin = 3.4e38f;
                #pragma unroll
                for (int k = 0; k < 8; ++k) {
                    if (k == i || k == j) continue;
                    v2 dk = p[k] - mid;
                    v2 sk = dk * dk;
                    dmin = fminf(dmin, sk.x + sk.y);
                }
                af[i][j] = (dmin < r2i) ? 0.0f : 1.0f;
                af[j][i] = (dmin < r2j) ? 0.0f : 1.0f;
            }
        }
    }

    // ---- degrees, dinv = rsqrt(rowsum(a_hat)) ----
    float dinv[8];
    #pragma unroll
    for (int i = 0; i < 8; ++i) {
        float s = ((af[i][0] + af[i][1]) + (af[i][2] + af[i][3])) +
                  ((af[i][4] + af[i][5]) + (af[i][6] + af[i][7]));
        dinv[i] = __builtin_amdgcn_rsqf(s);
    }

    // ---- q[j] = dinv_j * p[j];  n[i] = dinv_i * sum_j af[i][j] q[j] ----
    v2 q[8];
    #pragma unroll
    for (int j = 0; j < 8; ++j) q[j] = sp(dinv[j]) * p[j];

    v2 n[8];
    #pragma unroll
    for (int i = 0; i < 8; ++i) {
        v2 acc = sp(af[i][0]) * q[0];
        #pragma unroll
        for (int j = 1; j < 8; ++j) acc = fma2(sp(af[i][j]), q[j], acc);
        n[i] = sp(dinv[i]) * acc;
    }

    // ---- cj_j = 0.125 * dinv_j * sum_i af[i][j] * dinv_i (column sums) ----
    float cj[8];
    #pragma unroll
    for (int jp = 0; jp < 4; ++jp) {
        v2 acc = (v2){af[0][2 * jp], af[0][2 * jp + 1]} * sp(dinv[0]);
        #pragma unroll
        for (int i = 1; i < 8; ++i)
            acc = fma2((v2){af[i][2 * jp], af[i][2 * jp + 1]}, sp(dinv[i]), acc);
        v2 c2 = (sp(0.125f) * (v2){dinv[2 * jp], dinv[2 * jp + 1]}) * acc;
        cj[2 * jp] = c2.x; cj[2 * jp + 1] = c2.y;
    }

    // ---- GCN1 + pooled projection: t_f = sum_i cj_i * relu(h1[i][f]) ----
    v2 t2[16];
    #pragma unroll
    for (int fp = 0; fp < 16; ++fp) t2[fp] = sp(0.0f);
    #pragma unroll
    for (int i = 0; i < 8; ++i) {
        const v2 nxi = sp(n[i].x), nyi = sp(n[i].y), ci = sp(cj[i]);
        #pragma unroll
        for (int fp = 0; fp < 16; ++fp) {
            v2 h = fma2(nxi, ldv2(gcn1_w + 2 * fp),
                   fma2(nyi, ldv2(gcn1_w + 32 + 2 * fp), ldv2(gcn1_b + 2 * fp)));
            h = __builtin_elementwise_max(h, sp(0.0f));
            t2[fp] = fma2(ci, h, t2[fp]);
        }
    }

    // ---- pooled (packed g-pairs): pooled_g = t @ gcn2_w + gcn2_b ----
    v2 pooled2[16];
    #pragma unroll
    for (int gp = 0; gp < 16; ++gp) pooled2[gp] = ldv2(gcn2_b + 2 * gp);
    #pragma unroll
    for (int f = 0; f < 32; ++f) {
        const v2 tf = sp(t2[f >> 1][f & 1]);
        #pragma unroll
        for (int gp = 0; gp < 16; ++gp)
            pooled2[gp] = fma2(tf, ldv2(gcn2_w + f * 32 + 2 * gp), pooled2[gp]);
    }

    // ---- decoder (packed h-pairs): out = relu(pooled@W1+b1) . W2[:,1] + b2[1] ----
    v2 a2[32];
    #pragma unroll
    for (int hp = 0; hp < 32; ++hp) a2[hp] = ldv2(dec_b1 + 2 * hp);
    #pragma unroll
    for (int f = 0; f < 32; ++f) {
        const v2 pf = sp(pooled2[f >> 1][f & 1]);
        #pragma unroll
        for (int hp = 0; hp < 32; ++hp)
            a2[hp] = fma2(pf, ldv2(dec_w1 + f * 64 + 2 * hp), a2[hp]);
    }
    float o0 = 0.0f, o1 = 0.0f;
    #pragma unroll
    for (int hp = 0; hp < 32; ++hp) {
        v2 r = __builtin_elementwise_max(a2[hp], sp(0.0f));
        o0 = fmaf(r.x, dec_w2[(2 * hp) * 3 + 1], o0);
        o1 = fmaf(r.y, dec_w2[(2 * hp + 1) * 3 + 1], o1);
    }
    const float outv = (o0 + o1) + dec_b2[1];

    // ---- write reconstructed (same value for all 8 nodes) ----
    {
        float4 r4 = make_float4(outv, outv, outv, outv);
        float4* ro = reinterpret_cast<float4*>(out_rec + (size_t)b * 8);
        ro[0] = r4;
        ro[1] = r4;
    }
}

extern "C" void kernel_launch(void* const* d_in, const int* in_sizes, int n_in,
                              void* d_out, int out_size, void* d_ws, size_t ws_size,
                              hipStream_t stream) {
    const float* x       = (const float*)d_in[0];
    const float* enc_w1  = (const float*)d_in[1];
    const float* enc_b1  = (const float*)d_in[2];
    const float* enc_w2  = (const float*)d_in[3];
    const float* enc_b2  = (const float*)d_in[4];
    const float* gcn1_w  = (const float*)d_in[5];
    const float* gcn1_b  = (const float*)d_in[6];
    const float* gcn2_w  = (const float*)d_in[7];
    const float* gcn2_b  = (const float*)d_in[8];
    const float* dec_w1  = (const float*)d_in[9];
    const float* dec_b1  = (const float*)d_in[10];
    const float* dec_w2  = (const float*)d_in[11];
    const float* dec_b2  = (const float*)d_in[12];

    const int B = in_sizes[0] / 8;
    float* out_rec = (float*)d_out;                 // (B,8)
    float* out_lat = out_rec + (size_t)B * 8;       // (B,8,2)

    const int threads = 256;
    const int blocks  = (B + threads - 1) / threads;
    gae_kernel<<<blocks, threads, 0, stream>>>(
        x, enc_w1, enc_b1, enc_w2, enc_b2,
        gcn1_w, gcn1_b, gcn2_w, gcn2_b,
        dec_w1, dec_b1, dec_w2, dec_b2,
        out_rec, out_lat, B);
}

// Round 4
// 113.695 us; speedup vs baseline: 1.0597x; 1.0597x over previous
//
#include <hip/hip_runtime.h>

// GraphAutoEncoder: TWO threads per graph (B=131072, N=8), paired by WAVE:
// wave 2w = role 0, wave 2w+1 = role 1, same lane = same graph. Role is
// wave-uniform (readfirstlane) so all weight reads stay s_load/SGPR.
// Split: encoder by node-half, GCN1-t by feature-half, decoder by h-half;
// Gabriel graph + normalization duplicated (bit-identical to passing r2/r3).
// Aux kernel folds gcn2_w@dec_w1 (+bias, +dec_w2[:,1] gather) into d_ws:
// the pooled stage disappears (linear-linear fold; relu only after).

typedef float v2 __attribute__((ext_vector_type(2)));
static __device__ __forceinline__ v2 sp(float s) { return (v2){s, s}; }
static __device__ __forceinline__ v2 fma2(v2 a, v2 b, v2 c) {
    return __builtin_elementwise_fma(a, b, c);
}
static __device__ __forceinline__ v2 ldv2(const float* p) {
    return *reinterpret_cast<const v2*>(p);
}

// ws layout (floats): [0,2048) Wdec[32][64] = gcn2_w @ dec_w1
//                     [2048,2112) cdec[64]  = gcn2_b @ dec_w1 + dec_b1
//                     [2112,2176) w2col[64] = dec_w2[:,1]
__global__ __launch_bounds__(256) void gae_aux(
    const float* __restrict__ gcn2_w, const float* __restrict__ gcn2_b,
    const float* __restrict__ dec_w1, const float* __restrict__ dec_b1,
    const float* __restrict__ dec_w2, float* __restrict__ ws)
{
    const int tid = blockIdx.x * 256 + threadIdx.x;   // grid 8*256 = 2048
    const int f = tid >> 6, h = tid & 63;
    float acc = 0.0f;
    #pragma unroll 8
    for (int g = 0; g < 32; ++g)
        acc = fmaf(gcn2_w[f * 32 + g], dec_w1[g * 64 + h], acc);
    ws[f * 64 + h] = acc;
    if (tid < 64) {
        float c = dec_b1[h];
        #pragma unroll 8
        for (int g = 0; g < 32; ++g)
            c = fmaf(gcn2_b[g], dec_w1[g * 64 + h], c);
        ws[2048 + h] = c;
        ws[2112 + h] = dec_w2[h * 3 + 1];
    }
}

__global__ __launch_bounds__(256, 4) void gae_main(
    const float* __restrict__ x,        // (B,8)
    const float* __restrict__ enc_w1,   // (3,64)
    const float* __restrict__ enc_b1,   // (64,)
    const float* __restrict__ enc_w2,   // (64,2)
    const float* __restrict__ enc_b2,   // (2,)
    const float* __restrict__ gcn1_w,   // (2,32)
    const float* __restrict__ gcn1_b,   // (32,)
    const float* __restrict__ ws,       // folded decoder (see gae_aux)
    const float* __restrict__ dec_b2,   // (3,)
    float* __restrict__ out_rec,        // (B,8)
    float* __restrict__ out_lat,        // (B,8,2)
    int B)
{
    __shared__ v2    pbuf[2][8][64];    // latent exchange   (8 KB)
    __shared__ v2    tbuf[2][16][64];   // t exchange       (16 KB)
    __shared__ float obuf[2][2][64];    // outv exchange     (1 KB)

    const int lane = threadIdx.x & 63;
    const int wid  = threadIdx.x >> 6;          // 0..3
    const int wp   = wid >> 1;                  // wave-pair 0/1
    const int ru   = __builtin_amdgcn_readfirstlane(wid & 1);  // role, SGPR
    int g = blockIdx.x * 128 + wp * 64 + lane;  // graph id
    if (g >= B) g = B - 1;                      // clamp (grid is exact)

    // ---- load own 4 nodes' x (16B/lane, coalesced) ----
    const float4 xr = *reinterpret_cast<const float4*>(x + (size_t)g * 8 + 4 * ru);
    const v2 xA = (v2){xr.x, xr.y};
    const v2 xB = (v2){xr.z, xr.w};
    const float i0 = (float)(4 * ru);
    const v2 ipA = (v2){i0, i0 + 1.0f};
    const v2 ipB = (v2){i0 + 2.0f, i0 + 3.0f};

    // ---- encoder for own 4 nodes (bit-identical per-node arithmetic) ----
    v2 pl0, pl1, pl2, pl3;
    {
        const v2 b2v = ldv2(enc_b2);
        pl0 = b2v; pl1 = b2v; pl2 = b2v; pl3 = b2v;
    }
    #pragma unroll 4
    for (int h = 0; h < 64; ++h) {
        const float wx = enc_w1[64 + h];
        const float wi = enc_w1[128 + h];
        const float bb = enc_b1[h];
        const v2 uxy = ldv2(enc_w2 + 2 * h);
        v2 cA = fma2(ipA, sp(wi), sp(bb));
        v2 cB = fma2(ipB, sp(wi), sp(bb));
        v2 tA = fma2(xA, sp(wx), cA);
        v2 tB = fma2(xB, sp(wx), cB);
        tA = __builtin_elementwise_max(tA, sp(0.0f));
        tB = __builtin_elementwise_max(tB, sp(0.0f));
        pl0 = fma2(sp(tA.x), uxy, pl0);
        pl1 = fma2(sp(tA.y), uxy, pl1);
        pl2 = fma2(sp(tB.x), uxy, pl2);
        pl3 = fma2(sp(tB.y), uxy, pl3);
    }

    // ---- write own latent (B,8,2) ----
    {
        float4* lo = reinterpret_cast<float4*>(out_lat + (size_t)g * 16 + 8 * ru);
        lo[0] = make_float4(pl0.x, pl0.y, pl1.x, pl1.y);
        lo[1] = make_float4(pl2.x, pl2.y, pl3.x, pl3.y);
    }

    // ---- exchange latent: full p[8] on both roles ----
    pbuf[wp][4 * ru + 0][lane] = pl0;
    pbuf[wp][4 * ru + 1][lane] = pl1;
    pbuf[wp][4 * ru + 2][lane] = pl2;
    pbuf[wp][4 * ru + 3][lane] = pl3;
    __syncthreads();
    v2 p[8];
    #pragma unroll
    for (int j = 0; j < 8; ++j) p[j] = pbuf[wp][j][lane];

    // ---- Gabriel graph -> row bitmasks (diag = self loop), duplicated ----
    unsigned m[8];
    #pragma unroll
    for (int i = 0; i < 8; ++i) m[i] = 1u << i;
    {
        // Discrete decisions: no fma contraction; ops/order identical to the
        // passing r2/r3 kernels. r2 per DIRECTION (ulp-asymmetric, as ref).
        #pragma clang fp contract(off)
        #pragma unroll
        for (int i = 0; i < 8; ++i) {
            #pragma unroll
            for (int j = i + 1; j < 8; ++j) {
                v2 mid = (p[i] + p[j]) * sp(0.5f);
                v2 di = p[i] - mid;  v2 si = di * di;  float r2i = si.x + si.y;
                v2 dj = p[j] - mid;  v2 sj = dj * dj;  float r2j = sj.x + sj.y;
                float dmin = 3.4e38f;
                #pragma unroll
                for (int k = 0; k < 8; ++k) {
                    if (k == i || k == j) continue;
                    v2 dk = p[k] - mid;
                    v2 sk = dk * dk;
                    dmin = fminf(dmin, sk.x + sk.y);
                }
                m[i] |= (dmin < r2i) ? 0u : (1u << j);
                m[j] |= (dmin < r2j) ? 0u : (1u << i);
            }
        }
    }

    // ---- dinv, q, n (norm@latent), cj (column means) — duplicated ----
    float dinv[8];
    #pragma unroll
    for (int i = 0; i < 8; ++i)
        dinv[i] = __builtin_amdgcn_rsqf((float)__popc(m[i]));

    v2 q[8];
    #pragma unroll
    for (int j = 0; j < 8; ++j) q[j] = sp(dinv[j]) * p[j];

    v2 n[8];
    #pragma unroll
    for (int i = 0; i < 8; ++i) {
        v2 acc = sp(0.0f);
        #pragma unroll
        for (int j = 0; j < 8; ++j)
            acc = fma2(sp((float)((m[i] >> j) & 1u)), q[j], acc);
        n[i] = sp(dinv[i]) * acc;
    }

    float cj[8];
    #pragma unroll
    for (int j = 0; j < 8; ++j) {
        float s = 0.0f;
        #pragma unroll
        for (int i = 0; i < 8; ++i)
            s = fmaf((float)((m[i] >> j) & 1u), dinv[i], s);
        cj[j] = 0.125f * dinv[j] * s;
    }

    // ---- GCN1 + pooled projection, own 16 features (f in [16ru,16ru+16)) ----
    const float* w0 = gcn1_w + 16 * ru;
    const float* w1 = gcn1_w + 32 + 16 * ru;
    const float* bl = gcn1_b + 16 * ru;
    v2 t2[8];
    #pragma unroll
    for (int fp = 0; fp < 8; ++fp) t2[fp] = sp(0.0f);
    #pragma unroll
    for (int i = 0; i < 8; ++i) {
        const v2 nxi = sp(n[i].x), nyi = sp(n[i].y), ci = sp(cj[i]);
        #pragma unroll
        for (int fp = 0; fp < 8; ++fp) {
            v2 h = fma2(nxi, ldv2(w0 + 2 * fp),
                   fma2(nyi, ldv2(w1 + 2 * fp), ldv2(bl + 2 * fp)));
            h = __builtin_elementwise_max(h, sp(0.0f));
            t2[fp] = fma2(ci, h, t2[fp]);
        }
    }

    // ---- exchange t: full 32 features on both roles ----
    #pragma unroll
    for (int fp = 0; fp < 8; ++fp) tbuf[wp][8 * ru + fp][lane] = t2[fp];
    __syncthreads();
    v2 tf[16];
    #pragma unroll
    for (int fp = 0; fp < 16; ++fp) tf[fp] = tbuf[wp][fp][lane];

    // ---- folded decoder, own 32 h's: a_h = cdec_h + sum_f t_f Wdec[f][h] ----
    const float* Wd = ws + 32 * ru;           // row stride 64
    const float* cd = ws + 2048 + 32 * ru;
    const float* w2 = ws + 2112 + 32 * ru;
    v2 a2[16];
    #pragma unroll
    for (int hp = 0; hp < 16; ++hp) a2[hp] = ldv2(cd + 2 * hp);
    #pragma unroll
    for (int f = 0; f < 32; ++f) {
        const v2 pf = sp(tf[f >> 1][f & 1]);
        const float* wr = Wd + f * 64;
        #pragma unroll
        for (int hp = 0; hp < 16; ++hp)
            a2[hp] = fma2(pf, ldv2(wr + 2 * hp), a2[hp]);
    }
    v2 oacc = sp(0.0f);
    #pragma unroll
    for (int hp = 0; hp < 16; ++hp) {
        v2 rr = __builtin_elementwise_max(a2[hp], sp(0.0f));
        oacc = fma2(rr, ldv2(w2 + 2 * hp), oacc);
    }
    const float opart = oacc.x + oacc.y;

    // ---- combine partial outputs (commutative add -> both roles identical) ----
    obuf[wp][ru][lane] = opart;
    __syncthreads();
    const float outv = (opart + obuf[wp][1 - ru][lane]) + dec_b2[1];

    // ---- write reconstructed: own 4 nodes ----
    {
        float4 r4 = make_float4(outv, outv, outv, outv);
        *reinterpret_cast<float4*>(out_rec + (size_t)g * 8 + 4 * ru) = r4;
    }
}

extern "C" void kernel_launch(void* const* d_in, const int* in_sizes, int n_in,
                              void* d_out, int out_size, void* d_ws, size_t ws_size,
                              hipStream_t stream) {
    const float* x       = (const float*)d_in[0];
    const float* enc_w1  = (const float*)d_in[1];
    const float* enc_b1  = (const float*)d_in[2];
    const float* enc_w2  = (const float*)d_in[3];
    const float* enc_b2  = (const float*)d_in[4];
    const float* gcn1_w  = (const float*)d_in[5];
    const float* gcn1_b  = (const float*)d_in[6];
    const float* gcn2_w  = (const float*)d_in[7];
    const float* gcn2_b  = (const float*)d_in[8];
    const float* dec_w1  = (const float*)d_in[9];
    const float* dec_b1  = (const float*)d_in[10];
    const float* dec_w2  = (const float*)d_in[11];
    const float* dec_b2  = (const float*)d_in[12];

    const int B = in_sizes[0] / 8;
    float* out_rec = (float*)d_out;                 // (B,8)
    float* out_lat = out_rec + (size_t)B * 8;       // (B,8,2)
    float* ws      = (float*)d_ws;                  // needs 2176 floats

    gae_aux<<<8, 256, 0, stream>>>(gcn2_w, gcn2_b, dec_w1, dec_b1, dec_w2, ws);

    const int threads = 256;
    const int blocks  = (2 * B + threads - 1) / threads;
    gae_main<<<blocks, threads, 0, stream>>>(
        x, enc_w1, enc_b1, enc_w2, enc_b2,
        gcn1_w, gcn1_b, ws, dec_b2,
        out_rec, out_lat, B);
}

// Round 5
// 107.044 us; speedup vs baseline: 1.1255x; 1.0621x over previous
//
#include <hip/hip_runtime.h>

// GraphAutoEncoder: FOUR threads per graph (B=131072, N=8), one role per wave
// (wave w of block handles role w; lane L of all 4 waves = graph g).
// Role split: encoder 2 nodes, Gabriel 7 pairs, n/cj 2 rows/cols, GCN1 8
// features, folded decoder 16 h's. Exchanges via LDS (16 KB/block).
// __launch_bounds__(256,8): VGPR<=64 -> 8 waves/SIMD, grid = 8 blocks/CU.
// Latent arithmetic bit-identical to rounds 2-4 (same fma sequences).

typedef float v2 __attribute__((ext_vector_type(2)));
static __device__ __forceinline__ v2 sp(float s) { return (v2){s, s}; }
static __device__ __forceinline__ v2 fma2(v2 a, v2 b, v2 c) {
    return __builtin_elementwise_fma(a, b, c);
}
static __device__ __forceinline__ v2 ldv2(const float* p) {
    return *reinterpret_cast<const v2*>(p);
}

// ws layout (floats):
//   [0,2048)    Wdec[32][64] = gcn2_w @ dec_w1
//   [2048,2112) cdec[64]     = gcn2_b @ dec_w1 + dec_b1
//   [2112,2176) w2col[64]    = dec_w2[:,1]
//   [2176,2688) ctab[64][8]  : ctab[h*8+i] = fmaf(i, enc_w1[128+h], enc_b1[h])
__global__ __launch_bounds__(256) void gae_aux(
    const float* __restrict__ gcn2_w, const float* __restrict__ gcn2_b,
    const float* __restrict__ dec_w1, const float* __restrict__ dec_b1,
    const float* __restrict__ dec_w2, const float* __restrict__ enc_w1,
    const float* __restrict__ enc_b1, float* __restrict__ ws)
{
    const int tid = blockIdx.x * 256 + threadIdx.x;   // grid 8*256 = 2048
    const int f = tid >> 6, h = tid & 63;
    float acc = 0.0f;
    #pragma unroll 8
    for (int g = 0; g < 32; ++g)
        acc = fmaf(gcn2_w[f * 32 + g], dec_w1[g * 64 + h], acc);
    ws[f * 64 + h] = acc;
    if (tid < 64) {
        float c = dec_b1[h];
        #pragma unroll 8
        for (int g = 0; g < 32; ++g)
            c = fmaf(gcn2_b[g], dec_w1[g * 64 + h], c);
        ws[2048 + h] = c;
        ws[2112 + h] = dec_w2[h * 3 + 1];
    }
    if (tid < 512) {
        const int hh = tid >> 3, ii = tid & 7;
        ws[2176 + tid] = fmaf((float)ii, enc_w1[128 + hh], enc_b1[hh]);
    }
}

// Gabriel pair test, both directions. Op order identical to rounds 2-4.
template <int I, int J>
static __device__ __forceinline__ void gpair(const v2* __restrict__ p,
                                             unsigned& ml, unsigned& mh)
{
    #pragma clang fp contract(off)
    v2 mid = (p[I] + p[J]) * sp(0.5f);
    v2 di = p[I] - mid;  v2 si = di * di;  float r2i = si.x + si.y;
    v2 dj = p[J] - mid;  v2 sj = dj * dj;  float r2j = sj.x + sj.y;
    float dmin = 3.4e38f;
    #pragma unroll
    for (int k = 0; k < 8; ++k) {
        if (k == I || k == J) continue;
        v2 dk = p[k] - mid;
        v2 sk = dk * dk;
        dmin = fminf(dmin, sk.x + sk.y);
    }
    constexpr unsigned bi = 1u << (((I & 3) * 8) + J);  // row I, bit J
    constexpr unsigned bj = 1u << (((J & 3) * 8) + I);  // row J, bit I
    if (I < 4) ml |= (dmin < r2i) ? 0u : bi; else mh |= (dmin < r2i) ? 0u : bi;
    if (J < 4) ml |= (dmin < r2j) ? 0u : bj; else mh |= (dmin < r2j) ? 0u : bj;
}

__global__ __launch_bounds__(256, 8) void gae_main(
    const float* __restrict__ x,        // (B,8)
    const float* __restrict__ enc_w1,   // (3,64)
    const float* __restrict__ enc_w2,   // (64,2)
    const float* __restrict__ enc_b2,   // (2,)
    const float* __restrict__ gcn1_w,   // (2,32)
    const float* __restrict__ gcn1_b,   // (32,)
    const float* __restrict__ ws,       // folded tables (see gae_aux)
    const float* __restrict__ dec_b2,   // (3,)
    float* __restrict__ out_rec,        // (B,8)
    float* __restrict__ out_lat,        // (B,8,2)
    int B)
{
    __shared__ union { v2 p[8][64]; v2 t[16][64]; } ptb;          // 8 KB
    __shared__ union { unsigned m[4][2][64]; float o[4][64]; } mob; // 2 KB
    __shared__ v2    nbuf[8][64];                                  // 4 KB
    __shared__ float cjbuf[8][64];                                 // 2 KB

    const int lane = threadIdx.x & 63;
    const int ru   = __builtin_amdgcn_readfirstlane(threadIdx.x >> 6); // 0..3
    int g = blockIdx.x * 64 + lane;
    if (g >= B) g = B - 1;

    // ---- load own 2 nodes' x (8B/lane, coalesced) ----
    const float2 xr = *reinterpret_cast<const float2*>(x + (size_t)g * 8 + 2 * ru);
    const v2 xp2 = (v2){xr.x, xr.y};

    // ---- encoder, own 2 nodes (nodes 2ru, 2ru+1); bit-identical math ----
    const float* ctab = ws + 2176;
    v2 pl0, pl1;
    { const v2 b2v = ldv2(enc_b2); pl0 = b2v; pl1 = b2v; }
    #pragma unroll 8
    for (int h = 0; h < 64; ++h) {
        const float wx = enc_w1[64 + h];
        const v2 uxy = ldv2(enc_w2 + 2 * h);
        const v2 cpr = ldv2(ctab + h * 8 + 2 * ru);   // fmaf(i,wi,bb) pair
        v2 t = fma2(xp2, sp(wx), cpr);
        float t0 = fmaxf(t.x, 0.0f);
        float t1 = fmaxf(t.y, 0.0f);
        pl0 = fma2(sp(t0), uxy, pl0);
        pl1 = fma2(sp(t1), uxy, pl1);
    }

    // ---- write own latent (4 floats = 16B/lane) ----
    *reinterpret_cast<float4*>(out_lat + (size_t)g * 16 + 4 * ru) =
        make_float4(pl0.x, pl0.y, pl1.x, pl1.y);

    // ---- exchange latent ----
    ptb.p[2 * ru + 0][lane] = pl0;
    ptb.p[2 * ru + 1][lane] = pl1;
    __syncthreads();
    v2 p[8];
    #pragma unroll
    for (int j = 0; j < 8; ++j) p[j] = ptb.p[j][lane];

    // ---- Gabriel, 7 pairs per role -> partial packed row masks ----
    unsigned ml = 0u, mh = 0u;
    if (ru == 0) {
        gpair<0,1>(p, ml, mh); gpair<0,2>(p, ml, mh); gpair<0,3>(p, ml, mh);
        gpair<0,4>(p, ml, mh); gpair<0,5>(p, ml, mh); gpair<0,6>(p, ml, mh);
        gpair<0,7>(p, ml, mh);
    } else if (ru == 1) {
        gpair<1,2>(p, ml, mh); gpair<1,3>(p, ml, mh); gpair<1,4>(p, ml, mh);
        gpair<1,5>(p, ml, mh); gpair<1,6>(p, ml, mh); gpair<1,7>(p, ml, mh);
        gpair<2,3>(p, ml, mh);
    } else if (ru == 2) {
        gpair<2,4>(p, ml, mh); gpair<2,5>(p, ml, mh); gpair<2,6>(p, ml, mh);
        gpair<2,7>(p, ml, mh); gpair<3,4>(p, ml, mh); gpair<3,5>(p, ml, mh);
        gpair<3,6>(p, ml, mh);
    } else {
        gpair<3,7>(p, ml, mh); gpair<4,5>(p, ml, mh); gpair<4,6>(p, ml, mh);
        gpair<4,7>(p, ml, mh); gpair<5,6>(p, ml, mh); gpair<5,7>(p, ml, mh);
        gpair<6,7>(p, ml, mh);
    }

    // ---- combine masks (+ self loops) ----
    mob.m[ru][0][lane] = ml;
    mob.m[ru][1][lane] = mh;
    __syncthreads();
    ml = (mob.m[0][0][lane] | mob.m[1][0][lane]) |
         (mob.m[2][0][lane] | mob.m[3][0][lane]) | 0x08040201u;
    mh = (mob.m[0][1][lane] | mob.m[1][1][lane]) |
         (mob.m[2][1][lane] | mob.m[3][1][lane]) | 0x80402010u;

    // ---- dinv[8], q[8] (all compile-time indexed -> stays in regs) ----
    float dinv[8];
    v2 q[8];
    #pragma unroll
    for (int i = 0; i < 8; ++i) {
        const unsigned rb = ((i < 4 ? ml : mh) >> ((i & 3) * 8)) & 0xffu;
        dinv[i] = __builtin_amdgcn_rsqf((float)__popc(rb));
        q[i] = sp(dinv[i]) * p[i];
    }

    // ---- own 2 rows of n, own 2 cols of cj; publish to LDS ----
    {
        const unsigned w = (ru < 2) ? ml : mh;
        const int sh = ((2 * ru) & 3) * 8;
        const unsigned rb0 = (w >> sh) & 0xffu;
        const unsigned rb1 = (w >> (sh + 8)) & 0xffu;
        const float dv0 = __builtin_amdgcn_rsqf((float)__popc(rb0));
        const float dv1 = __builtin_amdgcn_rsqf((float)__popc(rb1));
        v2 a0 = sp(0.0f), a1 = sp(0.0f);
        #pragma unroll
        for (int j = 0; j < 8; ++j) {
            a0 = fma2(sp((float)((rb0 >> j) & 1u)), q[j], a0);
            a1 = fma2(sp((float)((rb1 >> j) & 1u)), q[j], a1);
        }
        nbuf[2 * ru + 0][lane] = sp(dv0) * a0;
        nbuf[2 * ru + 1][lane] = sp(dv1) * a1;

        const int j0 = 2 * ru, j1 = 2 * ru + 1;
        float s0 = 0.0f, s1 = 0.0f;
        #pragma unroll
        for (int i = 0; i < 8; ++i) {
            const unsigned rb = ((i < 4 ? ml : mh) >> ((i & 3) * 8)) & 0xffu;
            s0 = fmaf((float)((rb >> j0) & 1u), dinv[i], s0);
            s1 = fmaf((float)((rb >> j1) & 1u), dinv[i], s1);
        }
        cjbuf[j0][lane] = 0.125f * dv0 * s0;
        cjbuf[j1][lane] = 0.125f * dv1 * s1;
    }
    __syncthreads();

    // ---- GCN1 + pooled projection, own 8 features (f in [8ru, 8ru+8)) ----
    const float* w0 = gcn1_w + 8 * ru;
    const float* w1 = gcn1_w + 32 + 8 * ru;
    const float* bl = gcn1_b + 8 * ru;
    v2 t2[4];
    #pragma unroll
    for (int fp = 0; fp < 4; ++fp) t2[fp] = sp(0.0f);
    #pragma unroll
    for (int i = 0; i < 8; ++i) {
        const v2 ni = nbuf[i][lane];          // ds_read_b64
        const float ci = cjbuf[i][lane];      // ds_read_b32
        const v2 nxi = sp(ni.x), nyi = sp(ni.y), civ = sp(ci);
        #pragma unroll
        for (int fp = 0; fp < 4; ++fp) {
            v2 h = fma2(nxi, ldv2(w0 + 2 * fp),
                   fma2(nyi, ldv2(w1 + 2 * fp), ldv2(bl + 2 * fp)));
            h = __builtin_elementwise_max(h, sp(0.0f));
            t2[fp] = fma2(civ, h, t2[fp]);
        }
    }

    // ---- exchange t (reuses latent LDS region; two syncs since last read) ----
    #pragma unroll
    for (int fp = 0; fp < 4; ++fp) ptb.t[4 * ru + fp][lane] = t2[fp];
    __syncthreads();

    // ---- folded decoder, own 16 h's: a_h = cdec_h + sum_f t_f Wdec[f][h] ----
    const float* Wd = ws + 16 * ru;           // row stride 64
    const float* cd = ws + 2048 + 16 * ru;
    const float* w2 = ws + 2112 + 16 * ru;
    v2 a2[8];
    #pragma unroll
    for (int hp = 0; hp < 8; ++hp) a2[hp] = ldv2(cd + 2 * hp);
    #pragma unroll
    for (int fp = 0; fp < 16; ++fp) {
        const v2 tv = ptb.t[fp][lane];        // ds_read_b64
        const float* wrA = Wd + (2 * fp) * 64;
        const float* wrB = Wd + (2 * fp + 1) * 64;
        const v2 tA = sp(tv.x), tB = sp(tv.y);
        #pragma unroll
        for (int hp = 0; hp < 8; ++hp) {
            a2[hp] = fma2(tA, ldv2(wrA + 2 * hp), a2[hp]);
            a2[hp] = fma2(tB, ldv2(wrB + 2 * hp), a2[hp]);
        }
    }
    v2 oacc = sp(0.0f);
    #pragma unroll
    for (int hp = 0; hp < 8; ++hp) {
        v2 rr = __builtin_elementwise_max(a2[hp], sp(0.0f));
        oacc = fma2(rr, ldv2(w2 + 2 * hp), oacc);
    }
    const float opart = oacc.x + oacc.y;

    // ---- combine 4 partials (same order on all roles -> identical bits) ----
    mob.o[ru][lane] = opart;                  // mask region dead since GCN1
    __syncthreads();
    const float outv = ((mob.o[0][lane] + mob.o[1][lane]) +
                        (mob.o[2][lane] + mob.o[3][lane])) + dec_b2[1];

    // ---- write reconstructed, own 2 nodes (8B/lane) ----
    *reinterpret_cast<float2*>(out_rec + (size_t)g * 8 + 2 * ru) =
        make_float2(outv, outv);
}

extern "C" void kernel_launch(void* const* d_in, const int* in_sizes, int n_in,
                              void* d_out, int out_size, void* d_ws, size_t ws_size,
                              hipStream_t stream) {
    const float* x       = (const float*)d_in[0];
    const float* enc_w1  = (const float*)d_in[1];
    const float* enc_b1  = (const float*)d_in[2];
    const float* enc_w2  = (const float*)d_in[3];
    const float* enc_b2  = (const float*)d_in[4];
    const float* gcn1_w  = (const float*)d_in[5];
    const float* gcn1_b  = (const float*)d_in[6];
    const float* gcn2_w  = (const float*)d_in[7];
    const float* gcn2_b  = (const float*)d_in[8];
    const float* dec_w1  = (const float*)d_in[9];
    const float* dec_b1  = (const float*)d_in[10];
    const float* dec_w2  = (const float*)d_in[11];
    const float* dec_b2  = (const float*)d_in[12];

    const int B = in_sizes[0] / 8;
    float* out_rec = (float*)d_out;                 // (B,8)
    float* out_lat = out_rec + (size_t)B * 8;       // (B,8,2)
    float* ws      = (float*)d_ws;                  // needs 2688 floats

    gae_aux<<<8, 256, 0, stream>>>(gcn2_w, gcn2_b, dec_w1, dec_b1, dec_w2,
                                   enc_w1, enc_b1, ws);

    const int blocks = (B + 63) / 64;               // 64 graphs per block
    gae_main<<<blocks, 256, 0, stream>>>(
        x, enc_w1, enc_w2, enc_b2,
        gcn1_w, gcn1_b, ws, dec_b2,
        out_rec, out_lat, B);
}